// Round 5
// baseline (139.475 us; speedup 1.0000x reference)
//
#include <hip/hip_runtime.h>
#include <hip/hip_fp16.h>
#include <math.h>

#define CC 64
#define KK 16
#define NNODES 15
#define DD 512      // input feature dim
#define MM 512      // output dim
#define NN 16384    // rows

typedef _Float16 half8 __attribute__((ext_vector_type(8)));
typedef float f32x4 __attribute__((ext_vector_type(4)));
typedef unsigned long long u64;

// ---------------------------------------------------------------------------
// XLA/Eigen fast-tanh for f32 (bit-exact vs JAX's jnp.tanh lowering).
// ---------------------------------------------------------------------------
__device__ __forceinline__ float xla_tanhf(float x) {
    const float kMax = 7.90531110763549805f;
    bool tiny = fabsf(x) < 0.0004f;
    float xc = fminf(fmaxf(x, -kMax), kMax);
    float x2 = __fmul_rn(xc, xc);
    float p = __fmaf_rn(x2, -2.76076847742355e-16f, 2.00018790482477e-13f);
    p = __fmaf_rn(x2, p, -8.60467152213735e-11f);
    p = __fmaf_rn(x2, p, 5.12229709037114e-08f);
    p = __fmaf_rn(x2, p, 1.48572235717979e-05f);
    p = __fmaf_rn(x2, p, 6.37261928875436e-04f);
    p = __fmaf_rn(x2, p, 4.89352455891786e-03f);
    p = __fmul_rn(xc, p);
    float q = __fmaf_rn(x2, 1.19825839466702e-06f, 1.18534705686654e-04f);
    q = __fmaf_rn(x2, q, 2.26843463243900e-03f);
    q = __fmaf_rn(x2, q, 4.89352518554385e-03f);
    return tiny ? x : __fdiv_rn(p, q);
}

// ---------------------------------------------------------------------------
// Kernel 1: pack L (M, C, K) fp32 -> Bpk fp16 in MFMA-B fragment order.
// B operand of mfma_f32_16x16x32_f16: lane l holds B[k=(l>>4)*8+j][col=l&15],
// j = 0..7 packed in 4 VGPRs. Layout: Bpk[ks][mtile][lane] = uint4 (8 halves).
// (round-1 verified)
// ---------------------------------------------------------------------------
__global__ __launch_bounds__(256) void pack_bfrag(const float* __restrict__ L,
                                                  uint4* __restrict__ Bpk) {
    const int t    = blockIdx.x * 256 + threadIdx.x;  // 0..65535
    const int lane = t & 63;
    const int mtg  = (t >> 6) & 31;                   // global m-tile 0..31
    const int ks   = t >> 11;                         // k-step 0..31
    const int kbase = ks * 32 + ((lane >> 4) << 3);   // 8-aligned k window
    const int c     = kbase >> 4;                     // subspace
    const int slot0 = kbase & 15;                     // 0 or 8
    const int m     = (mtg << 4) + (lane & 15);

    const float* src = L + ((size_t)m * CC + c) * KK + slot0;
    float4 v0 = ((const float4*)src)[0];
    float4 v1 = ((const float4*)src)[1];
    union { half8 h; uint4 u; } pk;
    pk.h[0] = (_Float16)v0.x; pk.h[1] = (_Float16)v0.y;
    pk.h[2] = (_Float16)v0.z; pk.h[3] = (_Float16)v0.w;
    pk.h[4] = (_Float16)v1.x; pk.h[5] = (_Float16)v1.y;
    pk.h[6] = (_Float16)v1.z; pk.h[7] = (_Float16)v1.w;
    Bpk[t] = pk.u;
}

// ---------------------------------------------------------------------------
// Kernel 2: ENCODE (standalone). Grid 1024 x 256thr; thread (w,c) encodes
// rows {0,16,32,48}+w of its 64-row tile at subspace c (bit-exact round-5
// math), packs 4 codes into one u32 (byte rr), writes coalesced to codesG.
//
// R4 evidence for the split: fused kernel was 60% stall (VALU 27.7%, MFMA
// 11.3%, wall 56us) — encode->barrier->decode convoy + lockstep L2 misses.
// Standalone encode: no trailing barrier, no decode VGPRs. A-coeffs (32)
// and thresholds (15) hoisted to registers ONCE (fused version re-read sA
// per row: 128 ds_read_b32/thread ~ 5us/CU of LDS pipe).
// __launch_bounds__(256,4): arg2 = blocks/CU (R2 evidence) -> 16 waves/CU,
// 128-VGPR cap; est ~117 live. Spill tripwire: FETCH >> 21MB.
// ---------------------------------------------------------------------------
__global__ __launch_bounds__(256, 4) void encode_kernel(const float* __restrict__ I,
                                                        const float* __restrict__ A,
                                                        const float* __restrict__ T,
                                                        unsigned* __restrict__ codesG) {
    __shared__ float sA[32 * 64];              // TRANSPOSED: [s*4+d][c]
    __shared__ float sT[CC * NNODES];

    const int tid = threadIdx.x;
    for (int i = tid; i < CC * 32; i += 256) sA[(i & 31) * 64 + (i >> 5)] = A[i];
    for (int i = tid; i < CC * NNODES; i += 256) sT[i] = T[i];
    __syncthreads();

    const int lane = tid & 63;
    const int c    = lane;
    const int w    = ((blockIdx.x & 3) << 2) + (tid >> 6);   // 0..15
    const int tile = blockIdx.x >> 2;
    const int n0   = tile * 64;

    // hoist per-c constants to registers (read LDS once, not per row)
    float a_[32];
#pragma unroll
    for (int i = 0; i < 32; ++i) a_[i] = sA[i * 64 + c];     // conflict-free: bank=lane%32
    float tt[NNODES];
#pragma unroll
    for (int i = 0; i < NNODES; ++i) tt[i] = sT[c * NNODES + i];  // stride 15: 2-way, free

    const int lvl[NNODES] = {0, 1, 1, 2, 2, 2, 2, 3, 3, 3, 3, 3, 3, 3, 3};
    unsigned codeWord = 0;
#pragma unroll 2
    for (int rr = 0; rr < 4; ++rr) {
        const int rl = (rr << 4) + w;     // row_local 0..63
        const float* Ij = I + (size_t)(n0 + rl) * DD + c * 8;  // wave: 2KB contiguous
        float4 v0 = ((const float4*)Ij)[0];
        float4 v1 = ((const float4*)Ij)[1];
        float iv[8] = {v0.x, v0.y, v0.z, v0.w, v1.x, v1.y, v1.z, v1.w};

        float t[4] = {0.f, 0.f, 0.f, 0.f};
#pragma unroll
        for (int s = 0; s < 8; ++s) {
            float v = iv[s];
#pragma unroll
            for (int d = 0; d < 4; ++d)
                t[d] = __fmaf_rn(v, a_[(s << 2) + d], t[d]);
        }

        float th[NNODES];
#pragma unroll
        for (int i = 0; i < NNODES; ++i) {
            float h = __fsub_rn(t[lvl[i]], tt[i]);
            th[i] = xla_tanhf(h);
        }

        int best = 0;
        float bestv = -3.0e38f;
#pragma unroll
        for (int k = 0; k < KK; ++k) {
            int node = 0;
            float s = 0.f;
#pragma unroll
            for (int l = 0; l < 4; ++l) {
                int bit = (k >> (3 - l)) & 1;
                s = __fadd_rn(s, bit ? th[node] : -th[node]);
                node = 2 * node + 1 + bit;
            }
            if (s > bestv) { bestv = s; best = k; }   // strict >: first-max
        }
        codeWord |= ((unsigned)best) << (rr << 3);
    }
    // word [w][c] of the tile: byte rr = code of row rr*16+w (w == r15)
    codesG[(size_t)tile * 1024 + (w << 6) + c] = codeWord;   // 256B/wave coalesced
}

// ---------------------------------------------------------------------------
// Kernel 3: DECODE (standalone one-hot fp16 MFMA GEMM).
// Grid 1024 = (tile 0..255) x (mq 0..3); block 256thr = 4 waves; wave w =
// n-tile w over the SAME 128-col strip (mq*128): all 4 waves read IDENTICAL
// B frags per ks -> L1 hits. 4 blocks/CU, waves/SIMD come from 4 DIFFERENT
// blocks -> naturally staggered phases (no convoy), 16 waves/CU.
// Codes: 4KB tile loaded once to LDS. B ping-pong prefetch depth 1.
// VGPR est: bX/bY 64 + acc 32(AGPR) + ~20 = ~116 < 128 cap at (256,4).
// ---------------------------------------------------------------------------
__global__ __launch_bounds__(256, 4) void decode_kernel(const unsigned* __restrict__ codesG,
                                                        const uint4* __restrict__ Bpk,
                                                        float* __restrict__ out) {
    __shared__ unsigned sCodes[16 * 68];       // [r15][c] u32: byte nt = code of row nt*16+r15

    const int tid  = threadIdx.x;
    const int tile = blockIdx.x >> 2;
    const int mq   = blockIdx.x & 3;
    const int n0   = tile * 64;

#pragma unroll
    for (int kk = 0; kk < 4; ++kk) {
        int i = tid + (kk << 8);
        sCodes[(i >> 6) * 68 + (i & 63)] = codesG[(size_t)tile * 1024 + i];
    }
    __syncthreads();

    const int w    = tid >> 6;                  // wave = n-tile index wn (0..3)
    const int lane = tid & 63;
    const int wn   = w;
    const int r15  = lane & 15;
    const int sb   = ((lane >> 4) & 1) << 3;    // slot base (0 or 8) of lane's k-window
    const int chi  = lane >> 5;                 // which of the 2 subspaces per k-step
    const int wnsh = wn << 3;

    f32x4 acc[8];
#pragma unroll
    for (int mt = 0; mt < 8; ++mt) acc[mt] = (f32x4){0.f, 0.f, 0.f, 0.f};

    const uint4* Bp = Bpk + (size_t)(mq << 3) * 64 + lane;  // + (ks*32 + mt)*64 per frag
    const unsigned* codeRow = sCodes + r15 * 68;            // + (2*ks + chi) per k-step

    // ping-pong B buffers: bX holds even ks, bY odd ks
    uint4 bX[8], bY[8];
#pragma unroll
    for (int mt = 0; mt < 8; ++mt) bX[mt] = Bp[mt * 64];
    unsigned cwA = codeRow[chi];
    unsigned cwB;

    for (int ks = 0; ks < 32; ks += 2) {
        // prefetch ks+1 (ks <= 30: always valid)
#pragma unroll
        for (int mt = 0; mt < 8; ++mt) bY[mt] = Bp[((ks + 1) * 32 + mt) * 64];
        cwB = codeRow[(ks + 1) * 2 + chi];

        // ---- k-step ks: one-hot A from byte wn of cwA, MFMA vs bX ----
        {
            unsigned ud  = ((cwA >> wnsh) & 255u) - (unsigned)sb;
            unsigned ud2 = ud - 4u;
            u64 lo = (ud  < 4u) ? (0x3C00ull << ((ud  & 3u) << 4)) : 0ull;
            u64 hi = (ud2 < 4u) ? (0x3C00ull << ((ud2 & 3u) << 4)) : 0ull;
            union { u64 q[2]; half8 h; } uu; uu.q[0] = lo; uu.q[1] = hi;
#pragma unroll
            for (int mt = 0; mt < 8; ++mt) {
                union { uint4 u; half8 h; } bb; bb.u = bX[mt];
                acc[mt] = __builtin_amdgcn_mfma_f32_16x16x32_f16(uu.h, bb.h, acc[mt], 0, 0, 0);
            }
        }

        if (ks + 2 < 32) {
#pragma unroll
            for (int mt = 0; mt < 8; ++mt) bX[mt] = Bp[((ks + 2) * 32 + mt) * 64];
            cwA = codeRow[(ks + 2) * 2 + chi];
        }

        // ---- k-step ks+1: one-hot A from byte wn of cwB, MFMA vs bY ----
        {
            unsigned ud  = ((cwB >> wnsh) & 255u) - (unsigned)sb;
            unsigned ud2 = ud - 4u;
            u64 lo = (ud  < 4u) ? (0x3C00ull << ((ud  & 3u) << 4)) : 0ull;
            u64 hi = (ud2 < 4u) ? (0x3C00ull << ((ud2 & 3u) << 4)) : 0ull;
            union { u64 q[2]; half8 h; } uu; uu.q[0] = lo; uu.q[1] = hi;
#pragma unroll
            for (int mt = 0; mt < 8; ++mt) {
                union { uint4 u; half8 h; } bb; bb.u = bY[mt];
                acc[mt] = __builtin_amdgcn_mfma_f32_16x16x32_f16(uu.h, bb.h, acc[mt], 0, 0, 0);
            }
        }
    }

    // ---------------- epilogue: D layout col=lane&15, row=(lane>>4)*4+reg ----------------
    const int rbase = (lane >> 4) << 2;
#pragma unroll
    for (int mt = 0; mt < 8; ++mt) {
#pragma unroll
        for (int r = 0; r < 4; ++r) {
            out[(size_t)(n0 + (wn << 4) + rbase + r) * MM + (mq << 7) + (mt << 4) + r15] = acc[mt][r];
        }
    }
}

// ---------------------------------------------------------------------------
extern "C" void kernel_launch(void* const* d_in, const int* in_sizes, int n_in,
                              void* d_out, int out_size, void* d_ws, size_t ws_size,
                              hipStream_t stream) {
    const float* I = (const float*)d_in[0];  // (N, D) fp32
    const float* A = (const float*)d_in[1];  // (C, 8, 4) fp32
    const float* T = (const float*)d_in[2];  // (C*15,) fp32
    const float* L = (const float*)d_in[3];  // (M, C, K) fp32
    // d_in[4] = S, d_in[5] = B: structural constants, hard-coded.

    uint4* Bpk = (uint4*)d_ws;                              // 1 MB fp16 LUT frags
    unsigned* codesG = (unsigned*)((char*)d_ws + (1 << 20)); // 1 MB packed codes
    float* out = (float*)d_out;                              // (N, M) fp32

    hipLaunchKernelGGL(pack_bfrag, dim3(256), dim3(256), 0, stream, L, Bpk);
    hipLaunchKernelGGL(encode_kernel, dim3(1024), dim3(256), 0, stream, I, A, T, codesG);
    hipLaunchKernelGGL(decode_kernel, dim3(1024), dim3(256), 0, stream, codesG, Bpk, out);
}

// Round 8
// 128.941 us; speedup vs baseline: 1.0817x; 1.0817x over previous
//
#include <hip/hip_runtime.h>
#include <hip/hip_fp16.h>
#include <math.h>

#define CC 64
#define KK 16
#define NNODES 15
#define DD 512      // input feature dim
#define MM 512      // output dim
#define NN 16384    // rows

typedef _Float16 half8 __attribute__((ext_vector_type(8)));
typedef float f32x4 __attribute__((ext_vector_type(4)));
typedef unsigned long long u64;

// ---------------------------------------------------------------------------
// XLA/Eigen fast-tanh for f32 (bit-exact vs JAX's jnp.tanh lowering).
// ---------------------------------------------------------------------------
__device__ __forceinline__ float xla_tanhf(float x) {
    const float kMax = 7.90531110763549805f;
    bool tiny = fabsf(x) < 0.0004f;
    float xc = fminf(fmaxf(x, -kMax), kMax);
    float x2 = __fmul_rn(xc, xc);
    float p = __fmaf_rn(x2, -2.76076847742355e-16f, 2.00018790482477e-13f);
    p = __fmaf_rn(x2, p, -8.60467152213735e-11f);
    p = __fmaf_rn(x2, p, 5.12229709037114e-08f);
    p = __fmaf_rn(x2, p, 1.48572235717979e-05f);
    p = __fmaf_rn(x2, p, 6.37261928875436e-04f);
    p = __fmaf_rn(x2, p, 4.89352455891786e-03f);
    p = __fmul_rn(xc, p);
    float q = __fmaf_rn(x2, 1.19825839466702e-06f, 1.18534705686654e-04f);
    q = __fmaf_rn(x2, q, 2.26843463243900e-03f);
    q = __fmaf_rn(x2, q, 4.89352518554385e-03f);
    return tiny ? x : __fdiv_rn(p, q);
}

// ---------------------------------------------------------------------------
// Kernel 1: pack L (M, C, K) fp32 -> Bpk fp16 in MFMA-B fragment order.
// B operand of mfma_f32_16x16x32_f16: lane l holds B[k=(l>>4)*8+j][col=l&15],
// j = 0..7 packed in 4 VGPRs. Layout: Bpk[ks][mtile][lane] = uint4 (8 halves).
// (round-1 verified)
// ---------------------------------------------------------------------------
__global__ __launch_bounds__(256) void pack_bfrag(const float* __restrict__ L,
                                                  uint4* __restrict__ Bpk) {
    const int t    = blockIdx.x * 256 + threadIdx.x;  // 0..65535
    const int lane = t & 63;
    const int mtg  = (t >> 6) & 31;                   // global m-tile 0..31
    const int ks   = t >> 11;                         // k-step 0..31
    const int kbase = ks * 32 + ((lane >> 4) << 3);   // 8-aligned k window
    const int c     = kbase >> 4;                     // subspace
    const int slot0 = kbase & 15;                     // 0 or 8
    const int m     = (mtg << 4) + (lane & 15);

    const float* src = L + ((size_t)m * CC + c) * KK + slot0;
    float4 v0 = ((const float4*)src)[0];
    float4 v1 = ((const float4*)src)[1];
    union { half8 h; uint4 u; } pk;
    pk.h[0] = (_Float16)v0.x; pk.h[1] = (_Float16)v0.y;
    pk.h[2] = (_Float16)v0.z; pk.h[3] = (_Float16)v0.w;
    pk.h[4] = (_Float16)v1.x; pk.h[5] = (_Float16)v1.y;
    pk.h[6] = (_Float16)v1.z; pk.h[7] = (_Float16)v1.w;
    Bpk[t] = pk.u;
}

// ---------------------------------------------------------------------------
// Kernel 2: ENCODE (standalone, unchanged from round 5 — clean counters).
// ---------------------------------------------------------------------------
__global__ __launch_bounds__(256, 4) void encode_kernel(const float* __restrict__ I,
                                                        const float* __restrict__ A,
                                                        const float* __restrict__ T,
                                                        unsigned* __restrict__ codesG) {
    __shared__ float sA[32 * 64];              // TRANSPOSED: [s*4+d][c]
    __shared__ float sT[CC * NNODES];

    const int tid = threadIdx.x;
    for (int i = tid; i < CC * 32; i += 256) sA[(i & 31) * 64 + (i >> 5)] = A[i];
    for (int i = tid; i < CC * NNODES; i += 256) sT[i] = T[i];
    __syncthreads();

    const int lane = tid & 63;
    const int c    = lane;
    const int w    = ((blockIdx.x & 3) << 2) + (tid >> 6);   // 0..15
    const int tile = blockIdx.x >> 2;
    const int n0   = tile * 64;

    float a_[32];
#pragma unroll
    for (int i = 0; i < 32; ++i) a_[i] = sA[i * 64 + c];
    float tt[NNODES];
#pragma unroll
    for (int i = 0; i < NNODES; ++i) tt[i] = sT[c * NNODES + i];

    const int lvl[NNODES] = {0, 1, 1, 2, 2, 2, 2, 3, 3, 3, 3, 3, 3, 3, 3};
    unsigned codeWord = 0;
#pragma unroll 2
    for (int rr = 0; rr < 4; ++rr) {
        const int rl = (rr << 4) + w;
        const float* Ij = I + (size_t)(n0 + rl) * DD + c * 8;
        float4 v0 = ((const float4*)Ij)[0];
        float4 v1 = ((const float4*)Ij)[1];
        float iv[8] = {v0.x, v0.y, v0.z, v0.w, v1.x, v1.y, v1.z, v1.w};

        float t[4] = {0.f, 0.f, 0.f, 0.f};
#pragma unroll
        for (int s = 0; s < 8; ++s) {
            float v = iv[s];
#pragma unroll
            for (int d = 0; d < 4; ++d)
                t[d] = __fmaf_rn(v, a_[(s << 2) + d], t[d]);
        }

        float th[NNODES];
#pragma unroll
        for (int i = 0; i < NNODES; ++i) {
            float h = __fsub_rn(t[lvl[i]], tt[i]);
            th[i] = xla_tanhf(h);
        }

        int best = 0;
        float bestv = -3.0e38f;
#pragma unroll
        for (int k = 0; k < KK; ++k) {
            int node = 0;
            float s = 0.f;
#pragma unroll
            for (int l = 0; l < 4; ++l) {
                int bit = (k >> (3 - l)) & 1;
                s = __fadd_rn(s, bit ? th[node] : -th[node]);
                node = 2 * node + 1 + bit;
            }
            if (s > bestv) { bestv = s; best = k; }   // strict >: first-max
        }
        codeWord |= ((unsigned)best) << (rr << 3);
    }
    codesG[(size_t)tile * 1024 + (w << 6) + c] = codeWord;
}

// ---------------------------------------------------------------------------
// Kernel 3: DECODE — LDS-staged B (R5 evidence: per-wave register B streams
// gave 4 waves x 256KB x 1024 blocks = 1.07GB from L2 = 31us floor; MfmaUtil
// 14%, VALUBusy 12%, wall 43us). Fix: read B from L2 ONCE per block into
// LDS via global_load_lds (134MB total), every wave re-reads from LDS.
//
// Block = 128 rows x 128 cols, 4 waves (256 thr); wave = 4 nt x 4 mt
// (acc 64 VGPR). Grid 512 = 2 blocks/CU (independent barrier groups).
// 2-phase k-loop (guide T3 minimum): stage(ks+1) -> ds_read(ks) -> MFMA
// -> __syncthreads (drains vmcnt+lgkmcnt; stage had whole compute phase
// to cover L2 latency). One code word feeds all 4 nt builds (byte nt).
// __launch_bounds__(256,2): arg2 = blocks/CU (R2 evidence) -> 8 waves/CU,
// 256-VGPR cap, no spill risk (~100 live).
// ---------------------------------------------------------------------------
__global__ __launch_bounds__(256, 2) void decode_kernel(const unsigned* __restrict__ codesG,
                                                        const uint4* __restrict__ Bpk,
                                                        float* __restrict__ out) {
    __shared__ __align__(16) unsigned char sB[2][8192]; // [buf][frag 0..7][lane*16B]
    __shared__ unsigned sCodes[2][16 * 68];             // [rowhalf][r15*68 + c]

    const int tid = threadIdx.x;
    const int bn  = blockIdx.x >> 2;        // 0..127 (128-row group)
    const int bm  = blockIdx.x & 3;         // 0..3   (128-col strip)
    const int n0  = bn << 7;
    const int m0  = bm << 7;

    // ---- load 2048 code words (2 x 64-row tiles) into LDS ----
#pragma unroll
    for (int k = 0; k < 8; ++k) {
        int i = tid + (k << 8);             // 0..2047
        sCodes[i >> 10][((i >> 6) & 15) * 68 + (i & 63)] = codesG[((size_t)bn << 11) + i];
    }

    const int w    = tid >> 6;              // wave 0..3
    const int lane = tid & 63;
    const int wn   = w >> 1;                // row half (64 rows)
    const int wm   = w & 1;                 // col half (64 cols)
    const int r15  = lane & 15;
    const int sb   = ((lane >> 4) & 1) << 3;
    const int chi  = lane >> 5;

    // ---- staging: wave w owns frags w and w+4 of each k-step ----
    const uint4* gA = Bpk + ((bm << 3) + w) * 64 + lane;        // + ks*2048
    const uint4* gB = gA + 4 * 64;

    // prologue: stage ks=0 into buf 0
    __builtin_amdgcn_global_load_lds(
        (const __attribute__((address_space(1))) void*)gA,
        (__attribute__((address_space(3))) void*)&sB[0][w << 10], 16, 0, 0);
    __builtin_amdgcn_global_load_lds(
        (const __attribute__((address_space(1))) void*)gB,
        (__attribute__((address_space(3))) void*)&sB[0][(w + 4) << 10], 16, 0, 0);
    gA += 2048; gB += 2048;
    __syncthreads();   // covers sCodes writes + prologue stage

    f32x4 acc[4][4];
#pragma unroll
    for (int nt = 0; nt < 4; ++nt)
#pragma unroll
        for (int mt = 0; mt < 4; ++mt)
            acc[nt][mt] = (f32x4){0.f, 0.f, 0.f, 0.f};

    const unsigned* codeRow = &sCodes[wn][r15 * 68];   // + 2ks + chi
    const int bvoff = (wm << 2) << 10;                 // byte offset of this wave's 4 frags

#pragma unroll 2
    for (int ks = 0; ks < 32; ++ks) {
        const int cur = ks & 1;
        if (ks < 31) {
            __builtin_amdgcn_global_load_lds(
                (const __attribute__((address_space(1))) void*)gA,
                (__attribute__((address_space(3))) void*)&sB[cur ^ 1][w << 10], 16, 0, 0);
            __builtin_amdgcn_global_load_lds(
                (const __attribute__((address_space(1))) void*)gB,
                (__attribute__((address_space(3))) void*)&sB[cur ^ 1][(w + 4) << 10], 16, 0, 0);
            gA += 2048; gB += 2048;
        }

        const unsigned cw = codeRow[(ks << 1) + chi];

        uint4 b[4];
#pragma unroll
        for (int j = 0; j < 4; ++j)
            b[j] = *(const uint4*)&sB[cur][bvoff + (j << 10) + (lane << 4)];

#pragma unroll
        for (int nt = 0; nt < 4; ++nt) {
            unsigned ud  = ((cw >> (nt << 3)) & 255u) - (unsigned)sb;
            unsigned ud2 = ud - 4u;
            u64 lo = (ud  < 4u) ? (0x3C00ull << ((ud  & 3u) << 4)) : 0ull;
            u64 hi = (ud2 < 4u) ? (0x3C00ull << ((ud2 & 3u) << 4)) : 0ull;
            union { u64 q[2]; half8 h; } uu; uu.q[0] = lo; uu.q[1] = hi;
#pragma unroll
            for (int mt = 0; mt < 4; ++mt) {
                union { uint4 u; half8 h; } bb; bb.u = b[mt];
                acc[nt][mt] = __builtin_amdgcn_mfma_f32_16x16x32_f16(uu.h, bb.h, acc[nt][mt], 0, 0, 0);
            }
        }

        __syncthreads();   // drains stage(ks+1) vmcnt; guards buf reuse
    }

    // ---- epilogue: D layout col=lane&15, row=(lane>>4)*4+reg ----
    const int rbase = (lane >> 4) << 2;
#pragma unroll
    for (int nt = 0; nt < 4; ++nt) {
#pragma unroll
        for (int r = 0; r < 4; ++r) {
            float* o = out + (size_t)(n0 + ((wn << 2) + nt) * 16 + rbase + r) * MM
                           + m0 + (wm << 6) + r15;
#pragma unroll
            for (int mt = 0; mt < 4; ++mt)
                o[mt << 4] = acc[nt][mt][r];
        }
    }
}

// ---------------------------------------------------------------------------
extern "C" void kernel_launch(void* const* d_in, const int* in_sizes, int n_in,
                              void* d_out, int out_size, void* d_ws, size_t ws_size,
                              hipStream_t stream) {
    const float* I = (const float*)d_in[0];  // (N, D) fp32
    const float* A = (const float*)d_in[1];  // (C, 8, 4) fp32
    const float* T = (const float*)d_in[2];  // (C*15,) fp32
    const float* L = (const float*)d_in[3];  // (M, C, K) fp32
    // d_in[4] = S, d_in[5] = B: structural constants, hard-coded.

    uint4* Bpk = (uint4*)d_ws;                               // 1 MB fp16 LUT frags
    unsigned* codesG = (unsigned*)((char*)d_ws + (1 << 20)); // 1 MB packed codes
    float* out = (float*)d_out;                              // (N, M) fp32

    hipLaunchKernelGGL(pack_bfrag, dim3(256), dim3(256), 0, stream, L, Bpk);
    hipLaunchKernelGGL(encode_kernel, dim3(1024), dim3(256), 0, stream, I, A, T, codesG);
    hipLaunchKernelGGL(decode_kernel, dim3(512), dim3(256), 0, stream, codesG, Bpk, out);
}

// Round 11
// 123.265 us; speedup vs baseline: 1.1315x; 1.0460x over previous
//
#include <hip/hip_runtime.h>
#include <hip/hip_fp16.h>
#include <math.h>

#define CC 64
#define KK 16
#define NNODES 15
#define DD 512      // input feature dim
#define MM 512      // output dim
#define NN 16384    // rows

typedef _Float16 half8 __attribute__((ext_vector_type(8)));
typedef float f32x4 __attribute__((ext_vector_type(4)));
typedef unsigned long long u64;

// ---------------------------------------------------------------------------
// XLA/Eigen fast-tanh for f32 (bit-exact vs JAX's jnp.tanh lowering).
// ---------------------------------------------------------------------------
__device__ __forceinline__ float xla_tanhf(float x) {
    const float kMax = 7.90531110763549805f;
    bool tiny = fabsf(x) < 0.0004f;
    float xc = fminf(fmaxf(x, -kMax), kMax);
    float x2 = __fmul_rn(xc, xc);
    float p = __fmaf_rn(x2, -2.76076847742355e-16f, 2.00018790482477e-13f);
    p = __fmaf_rn(x2, p, -8.60467152213735e-11f);
    p = __fmaf_rn(x2, p, 5.12229709037114e-08f);
    p = __fmaf_rn(x2, p, 1.48572235717979e-05f);
    p = __fmaf_rn(x2, p, 6.37261928875436e-04f);
    p = __fmaf_rn(x2, p, 4.89352455891786e-03f);
    p = __fmul_rn(xc, p);
    float q = __fmaf_rn(x2, 1.19825839466702e-06f, 1.18534705686654e-04f);
    q = __fmaf_rn(x2, q, 2.26843463243900e-03f);
    q = __fmaf_rn(x2, q, 4.89352518554385e-03f);
    return tiny ? x : __fdiv_rn(p, q);
}

// ---------------------------------------------------------------------------
// Kernel 1: pack L (M, C, K) fp32 -> Bpk fp16 in MFMA-B fragment order.
// B operand of mfma_f32_16x16x32_f16: lane l holds B[k=(l>>4)*8+j][col=l&15],
// j = 0..7 packed in 4 VGPRs. Layout: Bpk[ks][mtile][lane] = uint4 (8 halves).
// (round-1 verified)
// ---------------------------------------------------------------------------
__global__ __launch_bounds__(256) void pack_bfrag(const float* __restrict__ L,
                                                  uint4* __restrict__ Bpk) {
    const int t    = blockIdx.x * 256 + threadIdx.x;  // 0..65535
    const int lane = t & 63;
    const int mtg  = (t >> 6) & 31;                   // global m-tile 0..31
    const int ks   = t >> 11;                         // k-step 0..31
    const int kbase = ks * 32 + ((lane >> 4) << 3);   // 8-aligned k window
    const int c     = kbase >> 4;                     // subspace
    const int slot0 = kbase & 15;                     // 0 or 8
    const int m     = (mtg << 4) + (lane & 15);

    const float* src = L + ((size_t)m * CC + c) * KK + slot0;
    float4 v0 = ((const float4*)src)[0];
    float4 v1 = ((const float4*)src)[1];
    union { half8 h; uint4 u; } pk;
    pk.h[0] = (_Float16)v0.x; pk.h[1] = (_Float16)v0.y;
    pk.h[2] = (_Float16)v0.z; pk.h[3] = (_Float16)v0.w;
    pk.h[4] = (_Float16)v1.x; pk.h[5] = (_Float16)v1.y;
    pk.h[6] = (_Float16)v1.z; pk.h[7] = (_Float16)v1.w;
    Bpk[t] = pk.u;
}

// ---------------------------------------------------------------------------
// Kernel 2: ENCODE (standalone, unchanged from round 5 — clean counters).
// ---------------------------------------------------------------------------
__global__ __launch_bounds__(256, 4) void encode_kernel(const float* __restrict__ I,
                                                        const float* __restrict__ A,
                                                        const float* __restrict__ T,
                                                        unsigned* __restrict__ codesG) {
    __shared__ float sA[32 * 64];              // TRANSPOSED: [s*4+d][c]
    __shared__ float sT[CC * NNODES];

    const int tid = threadIdx.x;
    for (int i = tid; i < CC * 32; i += 256) sA[(i & 31) * 64 + (i >> 5)] = A[i];
    for (int i = tid; i < CC * NNODES; i += 256) sT[i] = T[i];
    __syncthreads();

    const int lane = tid & 63;
    const int c    = lane;
    const int w    = ((blockIdx.x & 3) << 2) + (tid >> 6);   // 0..15
    const int tile = blockIdx.x >> 2;
    const int n0   = tile * 64;

    float a_[32];
#pragma unroll
    for (int i = 0; i < 32; ++i) a_[i] = sA[i * 64 + c];
    float tt[NNODES];
#pragma unroll
    for (int i = 0; i < NNODES; ++i) tt[i] = sT[c * NNODES + i];

    const int lvl[NNODES] = {0, 1, 1, 2, 2, 2, 2, 3, 3, 3, 3, 3, 3, 3, 3};
    unsigned codeWord = 0;
#pragma unroll 2
    for (int rr = 0; rr < 4; ++rr) {
        const int rl = (rr << 4) + w;
        const float* Ij = I + (size_t)(n0 + rl) * DD + c * 8;
        float4 v0 = ((const float4*)Ij)[0];
        float4 v1 = ((const float4*)Ij)[1];
        float iv[8] = {v0.x, v0.y, v0.z, v0.w, v1.x, v1.y, v1.z, v1.w};

        float t[4] = {0.f, 0.f, 0.f, 0.f};
#pragma unroll
        for (int s = 0; s < 8; ++s) {
            float v = iv[s];
#pragma unroll
            for (int d = 0; d < 4; ++d)
                t[d] = __fmaf_rn(v, a_[(s << 2) + d], t[d]);
        }

        float th[NNODES];
#pragma unroll
        for (int i = 0; i < NNODES; ++i) {
            float h = __fsub_rn(t[lvl[i]], tt[i]);
            th[i] = xla_tanhf(h);
        }

        int best = 0;
        float bestv = -3.0e38f;
#pragma unroll
        for (int k = 0; k < KK; ++k) {
            int node = 0;
            float s = 0.f;
#pragma unroll
            for (int l = 0; l < 4; ++l) {
                int bit = (k >> (3 - l)) & 1;
                s = __fadd_rn(s, bit ? th[node] : -th[node]);
                node = 2 * node + 1 + bit;
            }
            if (s > bestv) { bestv = s; best = k; }   // strict >: first-max
        }
        codeWord |= ((unsigned)best) << (rr << 3);
    }
    codesG[(size_t)tile * 1024 + (w << 6) + c] = codeWord;
}

// ---------------------------------------------------------------------------
// Kernel 3: DECODE v3 — register-staged, BARRIER-FREE.
// R8 evidence: LDS-staged decode ~32us (inferred from total delta). The
// per-k-step __syncthreads lowers to s_waitcnt vmcnt(0) lgkmcnt(0) +
// s_barrier and was issued right after the next-buffer stage -> FULL L2
// stage latency (~400-500cy) exposed EVERY k-step (m97-class drain), plus
// gload_lds->LDS->ds_read round trip, at only 2 waves/SIMD.
// R5's register-stream failure was TRAFFIC (1024 blocks x 8 frags = 1.07GB),
// not register staging: at THIS tiling (512 blocks, 4 frags/wave) register
// streams cost 268MB of L2 (~8us BW) — affordable.
//
// Block 128 rows x 128 cols, 4 waves; wave = 4nt x 4mt. Each wave loads its
// own 4 B-frags (16 VGPR) + 1 code word per k-step, FOUR k-steps deep in
// named register sets (rule-#20: no runtime-indexed arrays). No LDS, no
// barriers: waves are independent; compiler inserts counted vmcnt for
// reg-load deps. A load issued at slot ks completes under 3 compute slots.
// VGPR ~150 (< 256 cap at (256,2): 8 waves/CU). Spill tripwire: FETCH jump.
// ---------------------------------------------------------------------------
#define LOADSET(S, ks_)                              \
    b##S##0 = Bp[((ks_) * 32 + 0) * 64];             \
    b##S##1 = Bp[((ks_) * 32 + 1) * 64];             \
    b##S##2 = Bp[((ks_) * 32 + 2) * 64];             \
    b##S##3 = Bp[((ks_) * 32 + 3) * 64];             \
    c##S = cG[(ks_) << 1];

#define COMPUTESET(S) do {                                                        \
    const unsigned cw = c##S;                                                     \
    half8 a_[4];                                                                  \
    _Pragma("unroll")                                                             \
    for (int nt = 0; nt < 4; ++nt) {                                              \
        unsigned ud  = ((cw >> (nt << 3)) & 255u) - (unsigned)sb;                 \
        unsigned ud2 = ud - 4u;                                                   \
        u64 lo = (ud  < 4u) ? (0x3C00ull << ((ud  & 3u) << 4)) : 0ull;            \
        u64 hi = (ud2 < 4u) ? (0x3C00ull << ((ud2 & 3u) << 4)) : 0ull;            \
        union { u64 q[2]; half8 h; } uu; uu.q[0] = lo; uu.q[1] = hi;              \
        a_[nt] = uu.h;                                                            \
    }                                                                             \
    union { uint4 u; half8 h; } q0, q1, q2, q3;                                   \
    q0.u = b##S##0; q1.u = b##S##1; q2.u = b##S##2; q3.u = b##S##3;               \
    _Pragma("unroll")                                                             \
    for (int nt = 0; nt < 4; ++nt) {                                              \
        acc[nt][0] = __builtin_amdgcn_mfma_f32_16x16x32_f16(a_[nt], q0.h, acc[nt][0], 0, 0, 0); \
        acc[nt][1] = __builtin_amdgcn_mfma_f32_16x16x32_f16(a_[nt], q1.h, acc[nt][1], 0, 0, 0); \
        acc[nt][2] = __builtin_amdgcn_mfma_f32_16x16x32_f16(a_[nt], q2.h, acc[nt][2], 0, 0, 0); \
        acc[nt][3] = __builtin_amdgcn_mfma_f32_16x16x32_f16(a_[nt], q3.h, acc[nt][3], 0, 0, 0); \
    }                                                                             \
} while (0)

__global__ __launch_bounds__(256, 2) void decode_kernel(const unsigned* __restrict__ codesG,
                                                        const uint4* __restrict__ Bpk,
                                                        float* __restrict__ out) {
    const int tid = threadIdx.x;
    const int bn  = blockIdx.x >> 2;        // 0..127 (128-row group)
    const int bm  = blockIdx.x & 3;         // 0..3   (128-col strip)
    const int n0  = bn << 7;
    const int m0  = bm << 7;

    const int w    = tid >> 6;              // wave 0..3
    const int lane = tid & 63;
    const int wn   = w >> 1;                // row half (64 rows = one code tile)
    const int wm   = w & 1;                 // col half (64 cols = 4 m-tiles)
    const int r15  = lane & 15;
    const int sb   = ((lane >> 4) & 1) << 3;
    const int chi  = lane >> 5;

    // per-lane bases: B frag (ks,j) at Bp[(ks*32 + j)*64]; code word at cG[2ks]
    const uint4* Bp = Bpk + ((bm << 3) + (wm << 2)) * 64 + lane;
    const unsigned* cG = codesG + ((size_t)((bn << 1) | wn) << 10) + (r15 << 6) + chi;

    f32x4 acc[4][4];
#pragma unroll
    for (int nt = 0; nt < 4; ++nt)
#pragma unroll
        for (int mt = 0; mt < 4; ++mt)
            acc[nt][mt] = (f32x4){0.f, 0.f, 0.f, 0.f};

    uint4 bA0, bA1, bA2, bA3; unsigned cA;
    uint4 bB0, bB1, bB2, bB3; unsigned cB;
    uint4 bC0, bC1, bC2, bC3; unsigned cC;
    uint4 bD0, bD1, bD2, bD3; unsigned cD;

    // prologue: 4 k-steps in flight
    LOADSET(A, 0)
    LOADSET(B, 1)
    LOADSET(C, 2)
    LOADSET(D, 3)

#pragma unroll 1
    for (int g = 0; g < 8; ++g) {
        const int ks = g << 2;
        const bool more = g < 7;
        COMPUTESET(A); if (more) { LOADSET(A, ks + 4) }
        COMPUTESET(B); if (more) { LOADSET(B, ks + 5) }
        COMPUTESET(C); if (more) { LOADSET(C, ks + 6) }
        COMPUTESET(D); if (more) { LOADSET(D, ks + 7) }
    }

    // ---- epilogue: D layout col=lane&15, row=(lane>>4)*4+reg ----
    const int rbase = (lane >> 4) << 2;
#pragma unroll
    for (int nt = 0; nt < 4; ++nt) {
#pragma unroll
        for (int r = 0; r < 4; ++r) {
            float* o = out + (size_t)(n0 + ((wn << 2) + nt) * 16 + rbase + r) * MM
                           + m0 + (wm << 6) + r15;
#pragma unroll
            for (int mt = 0; mt < 4; ++mt)
                o[mt << 4] = acc[nt][mt][r];
        }
    }
}

// ---------------------------------------------------------------------------
extern "C" void kernel_launch(void* const* d_in, const int* in_sizes, int n_in,
                              void* d_out, int out_size, void* d_ws, size_t ws_size,
                              hipStream_t stream) {
    const float* I = (const float*)d_in[0];  // (N, D) fp32
    const float* A = (const float*)d_in[1];  // (C, 8, 4) fp32
    const float* T = (const float*)d_in[2];  // (C*15,) fp32
    const float* L = (const float*)d_in[3];  // (M, C, K) fp32
    // d_in[4] = S, d_in[5] = B: structural constants, hard-coded.

    uint4* Bpk = (uint4*)d_ws;                               // 1 MB fp16 LUT frags
    unsigned* codesG = (unsigned*)((char*)d_ws + (1 << 20)); // 1 MB packed codes
    float* out = (float*)d_out;                              // (N, M) fp32

    hipLaunchKernelGGL(pack_bfrag, dim3(256), dim3(256), 0, stream, L, Bpk);
    hipLaunchKernelGGL(encode_kernel, dim3(1024), dim3(256), 0, stream, I, A, T, codesG);
    hipLaunchKernelGGL(decode_kernel, dim3(512), dim3(256), 0, stream, codesG, Bpk, out);
}